// Round 8
// baseline (193.310 us; speedup 1.0000x reference)
//
#include <hip/hip_runtime.h>
#include <cstdint>

// Problem constants (from the reference)
#define LL    200
#define QQ    21
#define MM    1024
#define START 133        // 2*L//3
#define NS    67         // L - START
#define RGH   0.01f
#define RGJ   0.01f

// ws layout:
//   [0, 1024)              : accumulator slots (3 x 64 fp32)
//   [1024, +TOKP)          : tokP packed tokens, 4 j per dword, [jq][n]
//   [TOKP end, +SLAB)      : logit slab [iI][a][n], atomic-accumulated
#define SLOT_J2  0
#define SLOT_E   64
#define SLOT_LZ  128
#define TOKP_W   52
#define TOKP_OFF 1024
#define TOKP_BYTES ((size_t)TOKP_W * MM * 4)
#define SLAB_OFF (TOKP_OFF + TOKP_BYTES)
#define SLAB_FLOATS ((size_t)NS * QQ * MM)
#define SLAB_BYTES (SLAB_FLOATS * 4)
#define WS_FULL (SLAB_OFF + SLAB_BYTES)
#define WS_TOK  SLAB_OFF

// R7 model fit: LDS pipe is REQUEST-RATE saturated (~16 cyc/request at 16
// waves/CU, width-independent: b32/read2/b64 all plateau). Lever: fewer,
// fatter requests. Row stride 28 dw (112 B = 7x16B): row base 16B-aligned ->
// gather per (n,j) = 5 ds_read_b128 + 1 ds_read_b32 = 6 requests (was 11).
// Banks: gcd(28,32)=4 -> row starts cycle 8 distinct 4-bank groups (all 32
// banks); <=21 distinct rows/request (same-b lanes broadcast), 2-3 rows per
// group -> near-floor service.
// TJ=8 -> tile 169 x 28 = 4732 dw (18.9 kB); NBUF=2 = 37.9 kB/block ->
// launch_bounds(512,8) gives 4 blocks/CU: 2 z-paired p1 + 2 jsum fillers.
#define TJ 8
#define CPT (TJ * QQ)                  // 168 real columns
#define ROWDW 28                       // row stride (dwords), 112 B: 16B-aligned
#define DUMP_DW (CPT * ROWDW)          // dump row for invalid-thread writes
#define TILE_DW ((CPT + 1) * ROWDW + 4)  // 4736 dw = 18944 B
#define NBUF 2
#define BT 512
#define NWAVE 8

// Balanced p1 schedule: flatten (site, j-quad) -> [0, Tz) cut into NB_R
// equal ranges (~11 quads); block bx = (range bx&255, z-half bx>>8).
// z-pair blocks co-reside per CU and load identical J tiles (L2-hot).
#define NB_R  256
#define NB_P1 (2 * NB_R)               // 512
#define NB_JS 512
#define NB_TOKP 512

typedef float __attribute__((address_space(3)))* lf3_t;
typedef float __attribute__((ext_vector_type(4))) f32x4;

template <int NW>
__device__ __forceinline__ float block_reduce_sum(float v) {
  __shared__ float sm[NW];
  #pragma unroll
  for (int off = 32; off > 0; off >>= 1) v += __shfl_down(v, off, 64);
  const int lane = threadIdx.x & 63;
  const int wv   = threadIdx.x >> 6;
  __syncthreads();
  if (lane == 0) sm[wv] = v;
  __syncthreads();
  float r = 0.0f;
  if (threadIdx.x == 0) {
    #pragma unroll
    for (int k = 0; k < NW; ++k) r += sm[k];
  }
  return r;  // valid in thread 0 only
}

// ---------------------------------------------------------------------------
// Stage loads: thread tl covers global column gc = j0*21 + tl of plane
// [a][LL*QQ]; hi=0 waves load a=0..11 (12 rows), hi=1 waves a=12..20 (9).
// Lanes span gc -> 256 B coalesced per row. Invalid (tl>=168 | gc>=4200)
// -> safe Ji[0] (written to dump row, never gathered).
// ---------------------------------------------------------------------------
__device__ __forceinline__ void stage_load(
    const float* __restrict__ Ji, int j0, int tl, int hi, float (&jr)[12]) {
  const int gc = j0 * QQ + tl;
  const bool okc = (tl < CPT) && (gc < LL * QQ);
  const int a0 = hi ? 12 : 0;
  const int nr = hi ? 9 : 12;          // hi wave-uniform
  const float* g0 = Ji + (size_t)a0 * (LL * QQ) + gc;
  #pragma unroll
  for (int r = 0; r < 12; ++r) {
    if (r < nr) {
      const float* ga = okc ? (g0 + r * (LL * QQ)) : Ji;
      jr[r] = *ga;
    }
  }
}

// Writes: per-thread contiguous run at tile[tl*28 + (hi?12:0)]; both runs
// 16B-aligned (112*tl, +48 B) -> compiler merges to b128s; lane stride 28 dw
// -> 8 distinct 4-bank groups -> near-floor. Invalid threads -> dump row.
__device__ __forceinline__ void stage_write(
    float* __restrict__ wp, int hi, const float (&jr)[12]) {
  if (hi == 0) {
    #pragma unroll
    for (int r = 0; r < 12; ++r) wp[r] = jr[r];
  } else {
    #pragma unroll
    for (int r = 0; r < 9; ++r) wp[r] = jr[r];
  }
}

// ---------------------------------------------------------------------------
// Load the 2 packed token words covering tile at j0 (8 j's, j0 % 4 == 0).
// Fully-fake tiles (j0 >= jend) reload tile-0's words (never consumed).
// ---------------------------------------------------------------------------
template <int USET>
__device__ __forceinline__ void tok_words(
    const uint32_t* __restrict__ tokP, const int* __restrict__ Xtok,
    int j0, int jbeg, int jend, int n, uint32_t (&tw)[2]) {
  const int wbase = ((j0 < jend) ? j0 : jbeg) >> 2;
  #pragma unroll
  for (int wi = 0; wi < 2; ++wi) {
    int wq = wbase + wi;
    if constexpr (USET) {
      tw[wi] = tokP[wq * MM + n];        // words 50/51 = pad, never consumed
    } else {
      if (wq >= LL / 4) wq -= (LL / 4 - 1);   // keep in-bounds, distinct
      const int4 x = *reinterpret_cast<const int4*>(Xtok + n * LL + 4 * wq);
      tw[wi] = (uint32_t)x.x | ((uint32_t)x.y << 8)
             | ((uint32_t)x.z << 16) | ((uint32_t)x.w << 24);
    }
  }
}

// ---------------------------------------------------------------------------
// Gather one j: 21 consecutive dwords at tile[c*28] via 5 aligned b128 +
// 1 b32, single base reg + imm offsets (0..80 B). Rule #18: consume only
// after in-asm lgkmcnt(0) + sched_barrier(0).
// ---------------------------------------------------------------------------
#define RD128(dst, p, OFS) \
  asm volatile("ds_read_b128 %0, %1 offset:" #OFS \
               : "=v"(dst) : "v"((lf3_t)(p)))

__device__ __forceinline__ void gather_j(
    const float* __restrict__ tile, int c, float (&lg)[QQ]) {
  const float* p = tile + c * ROWDW;   // byte addr 112*c: 16B-aligned
  f32x4 g0, g1, g2, g3, g4;
  float g20;
  RD128(g0, p, 0);  RD128(g1, p, 16); RD128(g2, p, 32);
  RD128(g3, p, 48); RD128(g4, p, 64);
  asm volatile("ds_read_b32 %0, %1 offset:80" : "=v"(g20) : "v"((lf3_t)p));
  asm volatile("s_waitcnt lgkmcnt(0)" ::: "memory");
  __builtin_amdgcn_sched_barrier(0);
  lg[0]  += g0.x; lg[1]  += g0.y; lg[2]  += g0.z; lg[3]  += g0.w;
  lg[4]  += g1.x; lg[5]  += g1.y; lg[6]  += g1.z; lg[7]  += g1.w;
  lg[8]  += g2.x; lg[9]  += g2.y; lg[10] += g2.z; lg[11] += g2.w;
  lg[12] += g3.x; lg[13] += g3.y; lg[14] += g3.z; lg[15] += g3.w;
  lg[16] += g4.x; lg[17] += g4.y; lg[18] += g4.z; lg[19] += g4.w;
  lg[20] += g20;
}

// ---------------------------------------------------------------------------
// One segment: lg[a] += J[i,a,j,b(n,j)] over j in [jbeg, jend), jbeg%4==0.
// NBUF=2, one barrier/tile. Per iter: issue reg-stage loads (s+1) + token
// prefetch (s+2) BEFORE the gather (sched_barrier-pinned); write after the
// gather (compiler inserts the vmcnt wait at first jr use — covered by the
// gather). Early stores into buf[cur^1] are safe: its readers drained at
// the previous barrier.
// ---------------------------------------------------------------------------
template <int USET>
__device__ __forceinline__ void logz_seg(
    const float* __restrict__ Ji, const uint32_t* __restrict__ tokP,
    const int* __restrict__ Xtok, int jbeg, int jend, int n,
    float (*lds)[TILE_DW], float (&lg)[QQ], int t) {
  const int ntiles = (jend - jbeg + TJ - 1) / TJ;   // >= 1
  const int tl = t & 255, hi = t >> 8;              // hi wave-uniform
  const int wdw = (tl < CPT) ? (tl * ROWDW + (hi ? 12 : 0))
                             : (DUMP_DW + (hi ? 12 : 0));
  float* const wpA = &lds[0][wdw];
  float* const wpB = &lds[1][wdw];

  uint32_t cw[2], nx[2], nn[2];
  float jr[12];

  // Prologue: stage tile 0 into buf0; tokens for tiles 0,1.
  stage_load(Ji, jbeg, tl, hi, jr);
  tok_words<USET>(tokP, Xtok, jbeg, jbeg, jend, n, cw);
  tok_words<USET>(tokP, Xtok, jbeg + TJ, jbeg, jend, n, nx);
  stage_write(wpA, hi, jr);
  asm volatile("s_waitcnt lgkmcnt(0)" ::: "memory");
  __builtin_amdgcn_s_barrier();
  __builtin_amdgcn_sched_barrier(0);

  int cur = 0;
  for (int s = 0; s < ntiles; ++s) {
    const int rem  = min(TJ, jend - (jbeg + s * TJ));
    const bool more = (s + 1 < ntiles);             // block-uniform
    if (more) stage_load(Ji, jbeg + (s + 1) * TJ, tl, hi, jr);
    tok_words<USET>(tokP, Xtok, jbeg + (s + 2) * TJ, jbeg, jend, n, nn);
    __builtin_amdgcn_sched_barrier(0);              // pin loads above gather
    const float* tb = cur ? lds[1] : lds[0];
    #pragma unroll
    for (int jl = 0; jl < TJ; ++jl) {
      if (jl >= rem) break;                         // block-uniform
      const int b = (int)((cw[jl >> 2] >> ((jl & 3) * 8)) & 0xFF);
      gather_j(tb, jl * QQ + b, lg);
    }
    if (more) stage_write(cur ? wpA : wpB, hi, jr); // into buf[cur^1]
    #pragma unroll
    for (int wi = 0; wi < 2; ++wi) { cw[wi] = nx[wi]; nx[wi] = nn[wi]; }
    asm volatile("s_waitcnt lgkmcnt(0)" ::: "memory");
    __builtin_amdgcn_s_barrier();
    __builtin_amdgcn_sched_barrier(0);
    cur ^= 1;
  }
}

// ---------------------------------------------------------------------------
// p1 block: balanced quad-schedule per z-half. Range r owns quads
// [r*Tz/NB_R, (r+1)*Tz/NB_R); spans <=2 sites; atomic-flush into slab.
// ---------------------------------------------------------------------------
__device__ __forceinline__ void p1_block(
    const float* __restrict__ J, const uint32_t* __restrict__ tokP,
    float* __restrict__ slab, int bx, float (*lds)[TILE_DW]) {
  const int t = threadIdx.x;
  const int r = bx & (NB_R - 1);
  const int z = bx >> 8;

  int Tz = 0;                          // constant-folds
  #pragma unroll
  for (int s2 = 0; s2 < NS; ++s2) Tz += (START + s2 + 3) >> 2;

  int g  = (r * Tz) / NB_R;
  const int g1 = ((r + 1) * Tz) / NB_R;
  int iI = 0, pref = 0;
  while (pref + ((START + iI + 3) >> 2) <= g) {
    pref += (START + iI + 3) >> 2;
    ++iI;
  }
  int qlo = g - pref;

  float lg[QQ];
  #pragma unroll
  for (int a = 0; a < QQ; ++a) lg[a] = 0.0f;

  while (g < g1) {
    const int i    = START + iI;
    const int qcap = (i + 3) >> 2;
    int qhi = qlo + (g1 - g);
    if (qhi > qcap) qhi = qcap;
    const int jbeg = qlo * 4;
    int jend = qhi * 4; if (jend > i) jend = i;
    const int n = z * BT + t;
    const float* Ji = J + (size_t)i * (QQ * LL * QQ);

    logz_seg<1>(Ji, tokP, nullptr, jbeg, jend, n, lds, lg, t);

    float* dst = slab + ((size_t)iI * QQ) * MM + n;
    #pragma unroll
    for (int a = 0; a < QQ; ++a) { atomicAdd(dst + a * MM, lg[a]); lg[a] = 0.0f; }

    g += qhi - qlo;
    qlo = 0; ++iI;
  }
}

// ---------------------------------------------------------------------------
// jsum body: sum(J^2) stream + sum(J*fij) prefix rows, grid-strided by jb.
// ---------------------------------------------------------------------------
__device__ __forceinline__ void jsum_body(
    const float* __restrict__ J, const float* __restrict__ fij,
    float* __restrict__ acc, int jb) {
  const int t = threadIdx.x;
  const float4* __restrict__ J4 = (const float4*)J;
  float j2 = 0.0f;
  for (int f = jb * BT + t; f < (LL * QQ * LL * QQ / 4); f += NB_JS * BT) {
    const float4 v = J4[f];
    j2 += v.x * v.x + v.y * v.y + v.z * v.z + v.w * v.w;
  }
  float e = 0.0f;
  for (int r = jb; r < NS * QQ; r += NB_JS) {
    const int iI = r / QQ;
    const int a  = r - iI * QQ;
    const int i  = START + iI;
    const size_t base = (size_t)i * (QQ * LL * QQ) + (size_t)a * (LL * QQ);
    const float4* __restrict__ Jb = (const float4*)(J + base);
    const float4* __restrict__ Fb = (const float4*)(fij + base);
    const int lim  = i * QQ;
    const int lim4 = lim >> 2;
    for (int f = t; f < lim4; f += BT) {
      const float4 v = Jb[f], u = Fb[f];
      e += v.x * u.x + v.y * u.y + v.z * u.z + v.w * u.w;
    }
    const int rem = lim & 3;
    if (t < rem) {
      const int p = lim4 * 4 + t;
      e += (J + base)[p] * (fij + base)[p];
    }
  }
  const float tj2 = block_reduce_sum<NWAVE>(j2);
  const float te  = block_reduce_sum<NWAVE>(e);
  if (t == 0) {
    atomicAdd(acc + SLOT_J2 + (jb & 63), tj2);
    atomicAdd(acc + SLOT_E  + (jb & 63), te);
  }
}

// ---------------------------------------------------------------------------
// Fused kernel: blocks [0, NB_P1) = p1 (2 z-paired per CU), then jsum
// fillers (HBM-bound). launch_bounds(512,8): 4 blocks/CU (2 p1 + 2 jsum).
// ---------------------------------------------------------------------------
__global__ __launch_bounds__(BT, 8) void kern_mega(
    const float* __restrict__ J, const float* __restrict__ fij,
    const uint32_t* __restrict__ tokP, float* __restrict__ slab,
    float* __restrict__ acc) {
  __shared__ float lds[NBUF][TILE_DW];
  const int bx = blockIdx.x;
  if (bx < NB_P1) p1_block(J, tokP, slab, bx, lds);
  else            jsum_body(J, fij, acc, bx - NB_P1);
}

// ---------------------------------------------------------------------------
// Fallback (ws too small for slab): full-range mono blocks with in-kernel
// logsumexp. Grid (NS, 1, 2), z = blockIdx.z.
// ---------------------------------------------------------------------------
template <int USET>
__device__ __forceinline__ void mono_body(
    const float* __restrict__ J, const uint32_t* __restrict__ tokP,
    const int* __restrict__ Xtok, const float* __restrict__ h,
    const float* __restrict__ w, float* __restrict__ acc,
    float (*lds)[TILE_DW]) {
  const int iI = blockIdx.x;
  const int i  = START + iI;
  const int t  = threadIdx.x;
  const int n  = blockIdx.z * BT + t;
  float lg[QQ];
  #pragma unroll
  for (int a = 0; a < QQ; ++a) lg[a] = 0.0f;
  logz_seg<USET>(J + (size_t)i * (QQ * LL * QQ), tokP, Xtok, 0, i, n,
                 lds, lg, t);
  const float* hi = h + i * QQ;
  float mx = -3.0e38f;
  #pragma unroll
  for (int a = 0; a < QQ; ++a) { lg[a] += hi[a]; mx = fmaxf(mx, lg[a]); }
  float sme = 0.0f;
  #pragma unroll
  for (int a = 0; a < QQ; ++a) sme += expf(lg[a] - mx);
  const float contrib = w[n] * (mx + logf(sme));
  const float tot = block_reduce_sum<NWAVE>(contrib);
  if (t == 0) atomicAdd(acc + SLOT_LZ + (iI & 63), tot);
}

__global__ __launch_bounds__(BT) void kern_logz_mono_t(
    const float* __restrict__ J, const uint32_t* __restrict__ tokP,
    const float* __restrict__ h, const float* __restrict__ w,
    float* __restrict__ acc) {
  __shared__ float lds[NBUF][TILE_DW];
  mono_body<1>(J, tokP, nullptr, h, w, acc, lds);
}

__global__ __launch_bounds__(BT) void kern_logz_mono_x(
    const float* __restrict__ J, const int* __restrict__ Xtok,
    const float* __restrict__ h, const float* __restrict__ w,
    float* __restrict__ acc) {
  __shared__ float lds[NBUF][TILE_DW];
  mono_body<0>(J, nullptr, Xtok, h, w, acc, lds);
}

__global__ __launch_bounds__(BT) void kern_jsum(
    const float* __restrict__ J, const float* __restrict__ fij,
    float* __restrict__ acc) {
  jsum_body(J, fij, acc, blockIdx.x);
}

// ---------------------------------------------------------------------------
// Phase 2: slab + h -> logsumexp -> weighted sum (fence-free).
// ---------------------------------------------------------------------------
__global__ __launch_bounds__(128) void kern_logz_p2(
    const float* __restrict__ slab, const float* __restrict__ h,
    const float* __restrict__ w, float* __restrict__ acc) {
  const int iI = blockIdx.x;
  const int n  = blockIdx.y * 128 + threadIdx.x;
  const float* s0 = slab + ((size_t)iI * QQ) * MM + n;
  const float* hi = h + (START + iI) * QQ;
  float lg[QQ];
  float mx = -3.0e38f;
  #pragma unroll
  for (int a = 0; a < QQ; ++a) {
    lg[a] = s0[a * MM] + hi[a];
    mx = fmaxf(mx, lg[a]);
  }
  float sme = 0.0f;
  #pragma unroll
  for (int a = 0; a < QQ; ++a) sme += expf(lg[a] - mx);
  float v = w[n] * (mx + logf(sme));
  #pragma unroll
  for (int off = 32; off > 0; off >>= 1) v += __shfl_down(v, off, 64);
  __shared__ float sm[2];
  if ((threadIdx.x & 63) == 0) sm[threadIdx.x >> 6] = v;
  __syncthreads();
  if (threadIdx.x == 0)
    atomicAdd(acc + SLOT_LZ + ((iI * 8 + blockIdx.y) & 63), sm[0] + sm[1]);
}

// ---------------------------------------------------------------------------
// Token packing + accumulator/slab zeroing.
// ---------------------------------------------------------------------------
__global__ __launch_bounds__(256) void kern_tokP(
    const int* __restrict__ X, uint32_t* __restrict__ tokP,
    float* __restrict__ slab, float* __restrict__ acc, int zslab) {
  const int idx = blockIdx.x * 256 + threadIdx.x;
  if (blockIdx.x == 0) acc[threadIdx.x] = 0.0f;
  if (idx < (LL / 4) * MM) {
    const int jq = idx / MM;
    const int n  = idx - jq * MM;
    const int4 x = *reinterpret_cast<const int4*>(X + n * LL + 4 * jq);
    tokP[idx] = (uint32_t)x.x | ((uint32_t)x.y << 8)
              | ((uint32_t)x.z << 16) | ((uint32_t)x.w << 24);
  }
  if (zslab) {
    float4* s4 = (float4*)slab;
    const int nf4 = (int)(SLAB_FLOATS / 4);
    for (int q = idx; q < nf4; q += NB_TOKP * 256)
      s4[q] = make_float4(0.f, 0.f, 0.f, 0.f);
  }
}

// ---------------------------------------------------------------------------
// Final combine: slot sums + h-side terms + weight normalization.
// ---------------------------------------------------------------------------
__global__ __launch_bounds__(256) void kern_final(
    const float* __restrict__ h, const float* __restrict__ fi,
    const float* __restrict__ w, const float* __restrict__ acc,
    float* __restrict__ out) {
  const int t = threadIdx.x;
  const float sj2 = block_reduce_sum<4>(t < 64 ? acc[SLOT_J2 + t] : 0.0f);
  const float se  = block_reduce_sum<4>(t < 64 ? acc[SLOT_E + t] : 0.0f);
  const float slz = block_reduce_sum<4>(t < 64 ? acc[SLOT_LZ + t] : 0.0f);
  float hs = 0.0f, eh = 0.0f, ws = 0.0f;
  for (int idx = t; idx < LL * QQ; idx += 256) {
    const float hv = h[idx];
    hs += hv * hv;
    if (idx >= START * QQ) eh += fi[idx] * hv;
  }
  for (int idx = t; idx < MM; idx += 256) ws += w[idx];
  const float ths = block_reduce_sum<4>(hs);
  const float teh = block_reduce_sum<4>(eh);
  const float tws = block_reduce_sum<4>(ws);
  if (t == 0) {
    const float energy = teh + se;
    const float nll = slz / tws - energy;
    out[0] = nll + RGH * ths + RGJ * sj2;
    out[1] = nll;
  }
}

extern "C" void kernel_launch(void* const* d_in, const int* in_sizes, int n_in,
                              void* d_out, int out_size, void* d_ws, size_t ws_size,
                              hipStream_t stream) {
  const int*   Xtok = (const int*)  d_in[0];
  const float* wts  = (const float*)d_in[1];
  const float* fi   = (const float*)d_in[2];
  const float* fij  = (const float*)d_in[3];
  const float* h    = (const float*)d_in[4];
  const float* J    = (const float*)d_in[5];
  float* out  = (float*)d_out;
  float* acc  = (float*)d_ws;
  uint32_t* tokP = (uint32_t*)((char*)d_ws + TOKP_OFF);
  float* slab = (float*)((char*)d_ws + SLAB_OFF);

  if (ws_size >= WS_FULL) {
    kern_tokP<<<NB_TOKP, 256, 0, stream>>>(Xtok, tokP, slab, acc, 1);
    kern_mega<<<NB_P1 + NB_JS, BT, 0, stream>>>(J, fij, tokP, slab, acc);
    kern_logz_p2<<<dim3(NS, 8), 128, 0, stream>>>(slab, h, wts, acc);
    kern_final<<<1, 256, 0, stream>>>(h, fi, wts, acc, out);
  } else if (ws_size >= WS_TOK) {
    kern_tokP<<<NB_TOKP, 256, 0, stream>>>(Xtok, tokP, nullptr, acc, 0);
    kern_jsum<<<NB_JS, BT, 0, stream>>>(J, fij, acc);
    kern_logz_mono_t<<<dim3(NS, 1, 2), BT, 0, stream>>>(J, tokP, h, wts, acc);
    kern_final<<<1, 256, 0, stream>>>(h, fi, wts, acc, out);
  } else {
    hipMemsetAsync(d_ws, 0, 1024, stream);
    kern_jsum<<<NB_JS, BT, 0, stream>>>(J, fij, acc);
    kern_logz_mono_x<<<dim3(NS, 1, 2), BT, 0, stream>>>(J, Xtok, h, wts, acc);
    kern_final<<<1, 256, 0, stream>>>(h, fi, wts, acc, out);
  }
}

// Round 10
// 189.612 us; speedup vs baseline: 1.0195x; 1.0195x over previous
//
#include <hip/hip_runtime.h>
#include <cstdint>

// Problem constants (from the reference)
#define LL    200
#define QQ    21
#define MM    1024
#define START 133        // 2*L//3
#define NS    67         // L - START
#define RGH   0.01f
#define RGJ   0.01f

// ws layout:
//   [0, 1024)              : accumulator slots (3 x 64 fp32)
//   [1024, +TOKP)          : tokP packed tokens, 4 j per dword, [jq][n]
//   [TOKP end, +SLAB)      : logit slab [iI][a][n], atomic-accumulated
#define SLOT_J2  0
#define SLOT_E   64
#define SLOT_LZ  128
#define TOKP_W   52
#define TOKP_OFF 1024
#define TOKP_BYTES ((size_t)TOKP_W * MM * 4)
#define SLAB_OFF (TOKP_OFF + TOKP_BYTES)
#define SLAB_FLOATS ((size_t)NS * QQ * MM)
#define SLAB_BYTES (SLAB_FLOATS * 4)
#define WS_FULL (SLAB_OFF + SLAB_BYTES)
#define WS_TOK  SLAB_OFF

// R3/R5/R7/R8 model fit: in the broadcast-gather pattern the CU DS return
// path delivers ~30-33 LANE-bytes/cyc regardless of instruction width
// (b32 7.6 cyc/req, b64 ~16, b128 ~32 — cost scales exactly with width).
// => The only lever is FEWER LANE-BYTES: store the tile as fp16 pairs.
// Row [c = j*21+b] = 11 dwords: d=0..9 pack(J[a=2d], J[a=2d+1]), d=10
// pack(J[20], 0). Row stride 12 dw (48 B, 16B-aligned). Gather per (n,j):
// b128@0 + b128@16 + b64@32 + b32@40 = 44 lane-B (was 84) -> 1.9x less.
// Numerics: |J|~1e-4 (fp16-normal), pkrtz rel err <= 2^-10 -> logit err
// ~1e-6, final-loss err ~1e-6 (absmax moves off 0.0, far under tolerance).
// Unpack v_cvt_f32_f16 on VALU (3.7x headroom vs DS).
#define TJ 12
#define CPT (TJ * QQ)                  // 252 real columns (rows of the tile)
#define ROWDW 12                       // row stride in dwords (48 B)
#define DUMP_DW (CPT * ROWDW)          // dump row for invalid-thread writes
#define TILE_DW ((CPT + 1) * ROWDW + 4)  // 3040 dw = 12160 B
#define NBUF 2
#define BT 512
#define NWAVE 8

// Balanced p1 schedule: flatten (site, j-quad) -> [0, Tz) cut into NB_R
// equal ranges (~11 quads); block bx = (range bx&255, z-half bx>>8).
// z-pair blocks co-reside per CU and load identical J tiles (L2-hot).
#define NB_R  256
#define NB_P1 (2 * NB_R)               // 512
#define NB_JS 512
#define NB_TOKP 512

typedef float __attribute__((address_space(3)))* lf3_t;
typedef uint32_t __attribute__((ext_vector_type(4))) u32x4;
typedef uint32_t __attribute__((ext_vector_type(2))) u32x2;
typedef __fp16 __attribute__((ext_vector_type(2))) fp16x2;

// fp32 pair -> packed fp16 dword (v_cvt_pkrtz_f16_f32)
__device__ __forceinline__ uint32_t pk2(float x, float y) {
  union { fp16x2 h; uint32_t u; } c;
  c.h = __builtin_amdgcn_cvt_pkrtz(x, y);
  return c.u;
}
__device__ __forceinline__ float f16lo(uint32_t u) {
  union { unsigned short s; __fp16 h; } c;
  c.s = (unsigned short)(u & 0xffffu);
  return (float)c.h;
}
__device__ __forceinline__ float f16hi(uint32_t u) {
  union { unsigned short s; __fp16 h; } c;
  c.s = (unsigned short)(u >> 16);
  return (float)c.h;
}

template <int NW>
__device__ __forceinline__ float block_reduce_sum(float v) {
  __shared__ float sm[NW];
  #pragma unroll
  for (int off = 32; off > 0; off >>= 1) v += __shfl_down(v, off, 64);
  const int lane = threadIdx.x & 63;
  const int wv   = threadIdx.x >> 6;
  __syncthreads();
  if (lane == 0) sm[wv] = v;
  __syncthreads();
  float r = 0.0f;
  if (threadIdx.x == 0) {
    #pragma unroll
    for (int k = 0; k < NW; ++k) r += sm[k];
  }
  return r;  // valid in thread 0 only
}

// ---------------------------------------------------------------------------
// Stage loads: thread tl covers global column gc = j0*21 + tl of plane
// [a][LL*QQ]; hi=0 waves load a=0..11 (12 rows), hi=1 waves a=12..20 (9).
// Lanes span gc -> 256 B coalesced per row. Invalid (tl>=252 | gc>=4200)
// -> safe Ji[0] (written to dump row, never gathered).
// ---------------------------------------------------------------------------
__device__ __forceinline__ void stage_load(
    const float* __restrict__ Ji, int j0, int tl, int hi, float (&jr)[12]) {
  const int gc = j0 * QQ + tl;
  const bool okc = (tl < CPT) && (gc < LL * QQ);
  const int a0 = hi ? 12 : 0;
  const int nr = hi ? 9 : 12;          // hi wave-uniform
  const float* g0 = Ji + (size_t)a0 * (LL * QQ) + gc;
  #pragma unroll
  for (int r = 0; r < 12; ++r) {
    if (r < nr) {
      const float* ga = okc ? (g0 + r * (LL * QQ)) : Ji;
      jr[r] = *ga;
    }
  }
}

// Writes: convert fp32->fp16 pairs, then per-thread contiguous dword run:
// hi=0 -> dw 0..5 of the row (pairs a=(0,1)..(10,11)), hi=1 -> dw 6..10
// (pairs (12,13)..(18,19), then (20,0)). Both runs 8B-aligned (row base
// 48*tl, +24 B); lane stride 12 dw -> 8 distinct 4-bank groups.
__device__ __forceinline__ void stage_write(
    uint32_t* __restrict__ wp, int hi, const float (&jr)[12]) {
  if (hi == 0) {
    #pragma unroll
    for (int d = 0; d < 6; ++d) wp[d] = pk2(jr[2 * d], jr[2 * d + 1]);
  } else {
    #pragma unroll
    for (int d = 0; d < 4; ++d) wp[d] = pk2(jr[2 * d], jr[2 * d + 1]);
    wp[4] = pk2(jr[8], 0.0f);
  }
}

// ---------------------------------------------------------------------------
// Load the 3 packed token words covering tile at j0 (12 j's, j0 % 4 == 0).
// Fully-fake tiles (j0 >= jend) reload tile-0's words (never consumed).
// ---------------------------------------------------------------------------
template <int USET>
__device__ __forceinline__ void tok_words(
    const uint32_t* __restrict__ tokP, const int* __restrict__ Xtok,
    int j0, int jbeg, int jend, int n, uint32_t (&tw)[3]) {
  const int wbase = ((j0 < jend) ? j0 : jbeg) >> 2;
  #pragma unroll
  for (int wi = 0; wi < 3; ++wi) {
    int wq = wbase + wi;
    if constexpr (USET) {
      tw[wi] = tokP[wq * MM + n];        // words 50/51 = pad, never consumed
    } else {
      if (wq >= LL / 4) wq -= (LL / 4 - 1);   // keep in-bounds, distinct
      const int4 x = *reinterpret_cast<const int4*>(Xtok + n * LL + 4 * wq);
      tw[wi] = (uint32_t)x.x | ((uint32_t)x.y << 8)
             | ((uint32_t)x.z << 16) | ((uint32_t)x.w << 24);
    }
  }
}

// ---------------------------------------------------------------------------
// Gather one j: 11 packed dwords at tile[c*12] via b128+b128+b64+b32
// (44 lane-B vs 84 fp32). Rule #18: consume only after in-asm lgkmcnt(0)
// + sched_barrier(0). fp16->fp32 unpack on VALU.
// ---------------------------------------------------------------------------
__device__ __forceinline__ void gather_j(
    const float* __restrict__ tile, int c, float (&lg)[QQ]) {
  const float* p = tile + c * ROWDW;   // byte addr 48*c: 16B-aligned
  u32x4 g0, g1; u32x2 g2; uint32_t g3;
  asm volatile("ds_read_b128 %0, %1 offset:0"  : "=v"(g0) : "v"((lf3_t)p));
  asm volatile("ds_read_b128 %0, %1 offset:16" : "=v"(g1) : "v"((lf3_t)p));
  asm volatile("ds_read_b64 %0, %1 offset:32"  : "=v"(g2) : "v"((lf3_t)p));
  asm volatile("ds_read_b32 %0, %1 offset:40"  : "=v"(g3) : "v"((lf3_t)p));
  asm volatile("s_waitcnt lgkmcnt(0)" ::: "memory");
  __builtin_amdgcn_sched_barrier(0);
  lg[0]  += f16lo(g0.x); lg[1]  += f16hi(g0.x);
  lg[2]  += f16lo(g0.y); lg[3]  += f16hi(g0.y);
  lg[4]  += f16lo(g0.z); lg[5]  += f16hi(g0.z);
  lg[6]  += f16lo(g0.w); lg[7]  += f16hi(g0.w);
  lg[8]  += f16lo(g1.x); lg[9]  += f16hi(g1.x);
  lg[10] += f16lo(g1.y); lg[11] += f16hi(g1.y);
  lg[12] += f16lo(g1.z); lg[13] += f16hi(g1.z);
  lg[14] += f16lo(g1.w); lg[15] += f16hi(g1.w);
  lg[16] += f16lo(g2.x); lg[17] += f16hi(g2.x);
  lg[18] += f16lo(g2.y); lg[19] += f16hi(g2.y);
  lg[20] += f16lo(g3);
}

// ---------------------------------------------------------------------------
// One segment: lg[a] += J[i,a,j,b(n,j)] over j in [jbeg, jend), jbeg%4==0.
// NBUF=2, one barrier/tile. Per iter: issue reg-stage loads (s+1) + token
// prefetch (s+2) BEFORE the gather (sched_barrier-pinned); convert+write
// after the gather (compiler inserts the vmcnt wait at first jr use —
// covered by the gather). Early stores into buf[cur^1] are safe: its
// readers drained at the previous barrier.
// ---------------------------------------------------------------------------
template <int USET>
__device__ __forceinline__ void logz_seg(
    const float* __restrict__ Ji, const uint32_t* __restrict__ tokP,
    const int* __restrict__ Xtok, int jbeg, int jend, int n,
    float (*lds)[TILE_DW], float (&lg)[QQ], int t) {
  const int ntiles = (jend - jbeg + TJ - 1) / TJ;   // >= 1
  const int tl = t & 255, hi = t >> 8;              // hi wave-uniform
  const int wdw = ((tl < CPT) ? tl * ROWDW : DUMP_DW) + (hi ? 6 : 0);
  uint32_t* const wpA = (uint32_t*)&lds[0][wdw];
  uint32_t* const wpB = (uint32_t*)&lds[1][wdw];

  uint32_t cw[3], nx[3], nn[3];
  float jr[12];

  // Prologue: stage tile 0 into buf0; tokens for tiles 0,1.
  stage_load(Ji, jbeg, tl, hi, jr);
  tok_words<USET>(tokP, Xtok, jbeg, jbeg, jend, n, cw);
  tok_words<USET>(tokP, Xtok, jbeg + TJ, jbeg, jend, n, nx);
  stage_write(wpA, hi, jr);
  asm volatile("s_waitcnt lgkmcnt(0)" ::: "memory");
  __builtin_amdgcn_s_barrier();
  __builtin_amdgcn_sched_barrier(0);

  int cur = 0;
  for (int s = 0; s < ntiles; ++s) {
    const int rem  = min(TJ, jend - (jbeg + s * TJ));
    const bool more = (s + 1 < ntiles);             // block-uniform
    if (more) stage_load(Ji, jbeg + (s + 1) * TJ, tl, hi, jr);
    tok_words<USET>(tokP, Xtok, jbeg + (s + 2) * TJ, jbeg, jend, n, nn);
    __builtin_amdgcn_sched_barrier(0);              // pin loads above gather
    const float* tb = cur ? lds[1] : lds[0];
    #pragma unroll
    for (int jl = 0; jl < TJ; ++jl) {
      if (jl >= rem) break;                         // block-uniform
      const int b = (int)((cw[jl >> 2] >> ((jl & 3) * 8)) & 0xFF);
      gather_j(tb, jl * QQ + b, lg);
    }
    if (more) stage_write(cur ? wpA : wpB, hi, jr); // into buf[cur^1]
    #pragma unroll
    for (int wi = 0; wi < 3; ++wi) { cw[wi] = nx[wi]; nx[wi] = nn[wi]; }
    asm volatile("s_waitcnt lgkmcnt(0)" ::: "memory");
    __builtin_amdgcn_s_barrier();
    __builtin_amdgcn_sched_barrier(0);
    cur ^= 1;
  }
}

// ---------------------------------------------------------------------------
// p1 block: balanced quad-schedule per z-half. Range r owns quads
// [r*Tz/NB_R, (r+1)*Tz/NB_R); spans <=2 sites; atomic-flush into slab.
// ---------------------------------------------------------------------------
__device__ __forceinline__ void p1_block(
    const float* __restrict__ J, const uint32_t* __restrict__ tokP,
    float* __restrict__ slab, int bx, float (*lds)[TILE_DW]) {
  const int t = threadIdx.x;
  const int r = bx & (NB_R - 1);
  const int z = bx >> 8;

  int Tz = 0;                          // constant-folds
  #pragma unroll
  for (int s2 = 0; s2 < NS; ++s2) Tz += (START + s2 + 3) >> 2;

  int g  = (r * Tz) / NB_R;
  const int g1 = ((r + 1) * Tz) / NB_R;
  int iI = 0, pref = 0;
  while (pref + ((START + iI + 3) >> 2) <= g) {
    pref += (START + iI + 3) >> 2;
    ++iI;
  }
  int qlo = g - pref;

  float lg[QQ];
  #pragma unroll
  for (int a = 0; a < QQ; ++a) lg[a] = 0.0f;

  while (g < g1) {
    const int i    = START + iI;
    const int qcap = (i + 3) >> 2;
    int qhi = qlo + (g1 - g);
    if (qhi > qcap) qhi = qcap;
    const int jbeg = qlo * 4;
    int jend = qhi * 4; if (jend > i) jend = i;
    const int n = z * BT + t;
    const float* Ji = J + (size_t)i * (QQ * LL * QQ);

    logz_seg<1>(Ji, tokP, nullptr, jbeg, jend, n, lds, lg, t);

    float* dst = slab + ((size_t)iI * QQ) * MM + n;
    #pragma unroll
    for (int a = 0; a < QQ; ++a) { atomicAdd(dst + a * MM, lg[a]); lg[a] = 0.0f; }

    g += qhi - qlo;
    qlo = 0; ++iI;
  }
}

// ---------------------------------------------------------------------------
// jsum body: sum(J^2) stream + sum(J*fij) prefix rows, grid-strided by jb.
// ---------------------------------------------------------------------------
__device__ __forceinline__ void jsum_body(
    const float* __restrict__ J, const float* __restrict__ fij,
    float* __restrict__ acc, int jb) {
  const int t = threadIdx.x;
  const float4* __restrict__ J4 = (const float4*)J;
  float j2 = 0.0f;
  for (int f = jb * BT + t; f < (LL * QQ * LL * QQ / 4); f += NB_JS * BT) {
    const float4 v = J4[f];
    j2 += v.x * v.x + v.y * v.y + v.z * v.z + v.w * v.w;
  }
  float e = 0.0f;
  for (int r = jb; r < NS * QQ; r += NB_JS) {
    const int iI = r / QQ;
    const int a  = r - iI * QQ;
    const int i  = START + iI;
    const size_t base = (size_t)i * (QQ * LL * QQ) + (size_t)a * (LL * QQ);
    const float4* __restrict__ Jb = (const float4*)(J + base);
    const float4* __restrict__ Fb = (const float4*)(fij + base);
    const int lim  = i * QQ;
    const int lim4 = lim >> 2;
    for (int f = t; f < lim4; f += BT) {
      const float4 v = Jb[f], u = Fb[f];
      e += v.x * u.x + v.y * u.y + v.z * u.z + v.w * u.w;
    }
    const int rem = lim & 3;
    if (t < rem) {
      const int p = lim4 * 4 + t;
      e += (J + base)[p] * (fij + base)[p];
    }
  }
  const float tj2 = block_reduce_sum<NWAVE>(j2);
  const float te  = block_reduce_sum<NWAVE>(e);
  if (t == 0) {
    atomicAdd(acc + SLOT_J2 + (jb & 63), tj2);
    atomicAdd(acc + SLOT_E  + (jb & 63), te);
  }
}

// ---------------------------------------------------------------------------
// Fused kernel: blocks [0, NB_P1) = p1 (2 z-paired per CU), then jsum
// fillers (HBM-bound). launch_bounds(512,6): 3 blocks/CU (2 p1 + 1 jsum),
// VGPR cap ~85 (no spill risk; R5 precedent).
// ---------------------------------------------------------------------------
__global__ __launch_bounds__(BT, 6) void kern_mega(
    const float* __restrict__ J, const float* __restrict__ fij,
    const uint32_t* __restrict__ tokP, float* __restrict__ slab,
    float* __restrict__ acc) {
  __shared__ float lds[NBUF][TILE_DW];
  const int bx = blockIdx.x;
  if (bx < NB_P1) p1_block(J, tokP, slab, bx, lds);
  else            jsum_body(J, fij, acc, bx - NB_P1);
}

// ---------------------------------------------------------------------------
// Fallback (ws too small for slab): full-range mono blocks with in-kernel
// logsumexp. Grid (NS, 1, 2), z = blockIdx.z.
// ---------------------------------------------------------------------------
template <int USET>
__device__ __forceinline__ void mono_body(
    const float* __restrict__ J, const uint32_t* __restrict__ tokP,
    const int* __restrict__ Xtok, const float* __restrict__ h,
    const float* __restrict__ w, float* __restrict__ acc,
    float (*lds)[TILE_DW]) {
  const int iI = blockIdx.x;
  const int i  = START + iI;
  const int t  = threadIdx.x;
  const int n  = blockIdx.z * BT + t;
  float lg[QQ];
  #pragma unroll
  for (int a = 0; a < QQ; ++a) lg[a] = 0.0f;
  logz_seg<USET>(J + (size_t)i * (QQ * LL * QQ), tokP, Xtok, 0, i, n,
                 lds, lg, t);
  const float* hi = h + i * QQ;
  float mx = -3.0e38f;
  #pragma unroll
  for (int a = 0; a < QQ; ++a) { lg[a] += hi[a]; mx = fmaxf(mx, lg[a]); }
  float sme = 0.0f;
  #pragma unroll
  for (int a = 0; a < QQ; ++a) sme += expf(lg[a] - mx);
  const float contrib = w[n] * (mx + logf(sme));
  const float tot = block_reduce_sum<NWAVE>(contrib);
  if (t == 0) atomicAdd(acc + SLOT_LZ + (iI & 63), tot);
}

__global__ __launch_bounds__(BT) void kern_logz_mono_t(
    const float* __restrict__ J, const uint32_t* __restrict__ tokP,
    const float* __restrict__ h, const float* __restrict__ w,
    float* __restrict__ acc) {
  __shared__ float lds[NBUF][TILE_DW];
  mono_body<1>(J, tokP, nullptr, h, w, acc, lds);
}

__global__ __launch_bounds__(BT) void kern_logz_mono_x(
    const float* __restrict__ J, const int* __restrict__ Xtok,
    const float* __restrict__ h, const float* __restrict__ w,
    float* __restrict__ acc) {
  __shared__ float lds[NBUF][TILE_DW];
  mono_body<0>(J, nullptr, Xtok, h, w, acc, lds);
}

__global__ __launch_bounds__(BT) void kern_jsum(
    const float* __restrict__ J, const float* __restrict__ fij,
    float* __restrict__ acc) {
  jsum_body(J, fij, acc, blockIdx.x);
}

// ---------------------------------------------------------------------------
// Phase 2: slab + h -> logsumexp -> weighted sum (fence-free).
// ---------------------------------------------------------------------------
__global__ __launch_bounds__(128) void kern_logz_p2(
    const float* __restrict__ slab, const float* __restrict__ h,
    const float* __restrict__ w, float* __restrict__ acc) {
  const int iI = blockIdx.x;
  const int n  = blockIdx.y * 128 + threadIdx.x;
  const float* s0 = slab + ((size_t)iI * QQ) * MM + n;
  const float* hi = h + (START + iI) * QQ;
  float lg[QQ];
  float mx = -3.0e38f;
  #pragma unroll
  for (int a = 0; a < QQ; ++a) {
    lg[a] = s0[a * MM] + hi[a];
    mx = fmaxf(mx, lg[a]);
  }
  float sme = 0.0f;
  #pragma unroll
  for (int a = 0; a < QQ; ++a) sme += expf(lg[a] - mx);
  float v = w[n] * (mx + logf(sme));
  #pragma unroll
  for (int off = 32; off > 0; off >>= 1) v += __shfl_down(v, off, 64);
  __shared__ float sm[2];
  if ((threadIdx.x & 63) == 0) sm[threadIdx.x >> 6] = v;
  __syncthreads();
  if (threadIdx.x == 0)
    atomicAdd(acc + SLOT_LZ + ((iI * 8 + blockIdx.y) & 63), sm[0] + sm[1]);
}

// ---------------------------------------------------------------------------
// Token packing + accumulator/slab zeroing.
// ---------------------------------------------------------------------------
__global__ __launch_bounds__(256) void kern_tokP(
    const int* __restrict__ X, uint32_t* __restrict__ tokP,
    float* __restrict__ slab, float* __restrict__ acc, int zslab) {
  const int idx = blockIdx.x * 256 + threadIdx.x;
  if (blockIdx.x == 0) acc[threadIdx.x] = 0.0f;
  if (idx < (LL / 4) * MM) {
    const int jq = idx / MM;
    const int n  = idx - jq * MM;
    const int4 x = *reinterpret_cast<const int4*>(X + n * LL + 4 * jq);
    tokP[idx] = (uint32_t)x.x | ((uint32_t)x.y << 8)
              | ((uint32_t)x.z << 16) | ((uint32_t)x.w << 24);
  }
  if (zslab) {
    float4* s4 = (float4*)slab;
    const int nf4 = (int)(SLAB_FLOATS / 4);
    for (int q = idx; q < nf4; q += NB_TOKP * 256)
      s4[q] = make_float4(0.f, 0.f, 0.f, 0.f);
  }
}

// ---------------------------------------------------------------------------
// Final combine: slot sums + h-side terms + weight normalization.
// ---------------------------------------------------------------------------
__global__ __launch_bounds__(256) void kern_final(
    const float* __restrict__ h, const float* __restrict__ fi,
    const float* __restrict__ w, const float* __restrict__ acc,
    float* __restrict__ out) {
  const int t = threadIdx.x;
  const float sj2 = block_reduce_sum<4>(t < 64 ? acc[SLOT_J2 + t] : 0.0f);
  const float se  = block_reduce_sum<4>(t < 64 ? acc[SLOT_E + t] : 0.0f);
  const float slz = block_reduce_sum<4>(t < 64 ? acc[SLOT_LZ + t] : 0.0f);
  float hs = 0.0f, eh = 0.0f, ws = 0.0f;
  for (int idx = t; idx < LL * QQ; idx += 256) {
    const float hv = h[idx];
    hs += hv * hv;
    if (idx >= START * QQ) eh += fi[idx] * hv;
  }
  for (int idx = t; idx < MM; idx += 256) ws += w[idx];
  const float ths = block_reduce_sum<4>(hs);
  const float teh = block_reduce_sum<4>(eh);
  const float tws = block_reduce_sum<4>(ws);
  if (t == 0) {
    const float energy = teh + se;
    const float nll = slz / tws - energy;
    out[0] = nll + RGH * ths + RGJ * sj2;
    out[1] = nll;
  }
}

extern "C" void kernel_launch(void* const* d_in, const int* in_sizes, int n_in,
                              void* d_out, int out_size, void* d_ws, size_t ws_size,
                              hipStream_t stream) {
  const int*   Xtok = (const int*)  d_in[0];
  const float* wts  = (const float*)d_in[1];
  const float* fi   = (const float*)d_in[2];
  const float* fij  = (const float*)d_in[3];
  const float* h    = (const float*)d_in[4];
  const float* J    = (const float*)d_in[5];
  float* out  = (float*)d_out;
  float* acc  = (float*)d_ws;
  uint32_t* tokP = (uint32_t*)((char*)d_ws + TOKP_OFF);
  float* slab = (float*)((char*)d_ws + SLAB_OFF);

  if (ws_size >= WS_FULL) {
    kern_tokP<<<NB_TOKP, 256, 0, stream>>>(Xtok, tokP, slab, acc, 1);
    kern_mega<<<NB_P1 + NB_JS, BT, 0, stream>>>(J, fij, tokP, slab, acc);
    kern_logz_p2<<<dim3(NS, 8), 128, 0, stream>>>(slab, h, wts, acc);
    kern_final<<<1, 256, 0, stream>>>(h, fi, wts, acc, out);
  } else if (ws_size >= WS_TOK) {
    kern_tokP<<<NB_TOKP, 256, 0, stream>>>(Xtok, tokP, nullptr, acc, 0);
    kern_jsum<<<NB_JS, BT, 0, stream>>>(J, fij, acc);
    kern_logz_mono_t<<<dim3(NS, 1, 2), BT, 0, stream>>>(J, tokP, h, wts, acc);
    kern_final<<<1, 256, 0, stream>>>(h, fi, wts, acc, out);
  } else {
    (void)hipMemsetAsync(d_ws, 0, 1024, stream);
    kern_jsum<<<NB_JS, BT, 0, stream>>>(J, fij, acc);
    kern_logz_mono_x<<<dim3(NS, 1, 2), BT, 0, stream>>>(J, Xtok, h, wts, acc);
    kern_final<<<1, 256, 0, stream>>>(h, fi, wts, acc, out);
  }
}